// Round 8
// baseline (127.169 us; speedup 1.0000x reference)
//
#include <hip/hip_runtime.h>
#include <stdint.h>
#include <stddef.h>

// y[n,o] = sum_i x[n,i]*W[n,i,o] + b[n,o];  W = (x@Ww+bw) reshaped; b = x@Wb+bb.
// => Y = A@B (+bb): A[n, j*128+i] = x[n,i]*x[n,j]; B = Ww viewed [16384,128] row-major,
//    K-tail of 128: A[n,16384+i]=x[n,i], B[16384+i,o]=Wb[i,o]+bw[i*128+o].
// Per-j-phase factoring: aj = X_rows·B_j with raw-x fragments, acc += x[row,j]*aj.
// ROUND 15: r14 post-mortem — absmax error 67.5 == max|ref|: output all zeros, the
// cooperative launch NEVER RAN (hipLaunchCooperativeKernel fails under graph capture,
// error unchecked). Cooperative fusion is off the table. Revert to r13's proven
// 3-kernel structure, then cut non-gemm cost within the multi-kernel constraint:
//  (a) finish kernel DELETED: prep pre-fills out=bb (idempotent), gemm epilogue
//      atomicAdds into out (r7 proved ~6M device atomics into 4MB L2 region are fine).
//      g_P gone -> saves 37MB write + 37MB read + 1 launch + 1 drain.
//  (b) phase tail packed: xjv as floatx4, acc += xjv*aj as vector FMA (v_pk_fma_f32
//      opportunity) — tail was 64 scalar VALU/thread/phase ~= the MFMA issue time.
// Gemm core/grid/launch attrs byte-identical to r13 (protect VGPR=116 codegen).

#define NROWS   8192
#define NKT     516            // (16384+128)/32 K-tiles
#define TILE_E  4096           // 128 cols x 32 kk per K-tile image (u16)
#define XS_STRIDE 136          // 128 + 8 pad for LDS x tile
#define LS_STRIDE 136
#define BM      128
#define NSLICE  8

typedef unsigned short u16;
typedef short short8 __attribute__((ext_vector_type(8)));
typedef unsigned short ushort8 __attribute__((ext_vector_type(8)));
typedef float floatx4 __attribute__((ext_vector_type(4)));

// Module-scope scratch (BSS; independent of d_ws — rounds 1-3 showed ws hazards).
__device__ __align__(16) u16 g_B[(size_t)NKT * TILE_E];   // 4.2 MB bf16 B image

__device__ __forceinline__ u16 f2bf_rne(float f) {
    unsigned int u = __float_as_uint(f);
    u += 0x7fffu + ((u >> 16) & 1u);
    return (u16)(u >> 16);
}

// ---------------- prep: g_B[kt][o][kk] = B[kt*32+kk][o], coalesced via LDS transpose;
//                  also pre-fills out with broadcast bb (kt<512 blocks). ----------------
__global__ __launch_bounds__(256) void prep_kernel(
    const float* __restrict__ Ww, const float* __restrict__ Wb,
    const float* __restrict__ bw, const float* __restrict__ bb,
    float* __restrict__ out)
{
    __shared__ __align__(16) u16 ls[32 * LS_STRIDE];
    const int kt = blockIdx.x;
    const int t  = threadIdx.x;

    // out = bb broadcast (512 of 516 blocks cover 8192*128 floats, 8 each)
    if (kt < 512) {
        const int flat = (kt*256 + t) * 8;
        const floatx4 b0 = *(const floatx4*)(bb + (flat & 127));
        const floatx4 b1 = *(const floatx4*)(bb + (flat & 127) + 4);
        *(floatx4*)(out + flat)     = b0;
        *(floatx4*)(out + flat + 4) = b1;
    }

    // load 16 contiguous floats -> bf16, store to ls[kk][o] (padded stride)
    float v[16];
    if (kt < 512) {
        const float* src = Ww + (size_t)(kt >> 2)*16384 + (size_t)(kt & 3)*32*128 + t*16;
#pragma unroll
        for (int c = 0; c < 4; ++c) {
            const floatx4 f4 = *(const floatx4*)(src + c*4);
#pragma unroll
            for (int e = 0; e < 4; ++e) v[c*4 + e] = f4[e];
        }
    } else {
        const size_t base = (size_t)(kt - 512)*32*128 + t*16;
        const float* s1 = Wb + base;
        const float* s2 = bw + base;
#pragma unroll
        for (int c = 0; c < 4; ++c) {
            const floatx4 a = *(const floatx4*)(s1 + c*4);
            const floatx4 b = *(const floatx4*)(s2 + c*4);
#pragma unroll
            for (int e = 0; e < 4; ++e) v[c*4 + e] = a[e] + b[e];
        }
    }
    {
        const int kk = t >> 3;            // f = t*16 -> kk = f>>7
        const int o0 = (t & 7) * 16;      // f & 127
        ushort8 w0, w1;
#pragma unroll
        for (int e = 0; e < 8; ++e) { w0[e] = f2bf_rne(v[e]); w1[e] = f2bf_rne(v[8+e]); }
        *(ushort8*)&ls[kk*LS_STRIDE + o0]     = w0;
        *(ushort8*)&ls[kk*LS_STRIDE + o0 + 8] = w1;
    }
    __syncthreads();
    // write out [o][kk]: thread t covers d = t*16..+15 -> o = t>>1, kk = (t&1)*16..+15
    {
        const int o   = t >> 1;
        const int kk0 = (t & 1) * 16;
        ushort8 w0, w1;
#pragma unroll
        for (int e = 0; e < 8; ++e) {
            w0[e] = ls[(kk0 + e)*LS_STRIDE + o];
            w1[e] = ls[(kk0 + 8 + e)*LS_STRIDE + o];
        }
        u16* outp = g_B + (size_t)kt*TILE_E + t*16;
        ((ushort8*)outp)[0] = w0; ((ushort8*)outp)[1] = w1;
    }
}

// ---------------- gemm: 64x32 wave tile, full-phase double-buffered B prefetch --------
// grid 1024 = slice(8) x rowblock(64) x cg(2); block tile 128 rows x 64 cols.
// slice = b>>7: consecutive block IDs share slice (r7/r10/r13-proven ordering).
// Epilogue: device-scope atomicAdd into out (pre-filled with bb by prep).
__global__ __launch_bounds__(256)
__attribute__((amdgpu_waves_per_eu(2, 8)))
void gemm_kernel(const float* __restrict__ x, float* __restrict__ out)
{
    __shared__ __align__(16) u16 xs[BM * XS_STRIDE];

    const int b     = blockIdx.x;
    const int slice = b >> 7;         // 0..7
    const int rem   = b & 127;
    const int rb    = rem >> 1;       // 0..63
    const int cg    = rem & 1;        // col group: cols [cg*64, cg*64+64)
    const int row0  = rb * BM;
    const int tid   = threadIdx.x;
    const int lane  = tid & 63;
    const int wave  = tid >> 6;
    const int wm    = wave >> 1;      // row group: rows [wm*64, +64)
    const int wc    = wave & 1;       // col subgroup: 32 cols
    const int l15   = lane & 15;
    const int q     = lane >> 4;

    // stage x[row0..+128)[0..128) fp32 -> bf16 xs (conversion fused here)
#pragma unroll
    for (int it = 0; it < 8; ++it) {
        const int c  = it*256 + tid;
        const int r  = c >> 4;
        const int c8 = (c & 15) * 8;
        const float* sp = x + ((size_t)(row0 + r) << 7) + c8;
        const floatx4 f0 = *(const floatx4*)(sp);
        const floatx4 f1 = *(const floatx4*)(sp + 4);
        ushort8 w;
#pragma unroll
        for (int e = 0; e < 4; ++e) { w[e] = f2bf_rne(f0[e]); w[4+e] = f2bf_rne(f1[e]); }
        *(ushort8*)&xs[r*XS_STRIDE + c8] = w;
    }
    __syncthreads();

    // A-fragments cached (phase-invariant): af[ks][mt], A[m=l15][k=q*8+e]
    short8 af[4][4];
#pragma unroll
    for (int ks = 0; ks < 4; ++ks)
#pragma unroll
        for (int mt = 0; mt < 4; ++mt)
            af[ks][mt] = *(const short8*)&xs[(wm*64 + mt*16 + l15)*XS_STRIDE + ks*32 + q*8];

    const floatx4 fzero = {0.f, 0.f, 0.f, 0.f};
    floatx4 acc[4][2];
#pragma unroll
    for (int i = 0; i < 4; ++i) { acc[i][0] = fzero; acc[i][1] = fzero; }

    // phase partition: 129 phases over 8 slices (17,16,16,16,16,16,16,16)
    const int p0 = slice*16 + (slice ? 1 : 0);
    const int np = slice ? 16 : 17;

    const int colbase = cg*64 + wc*32;
    const size_t loff = (size_t)(colbase + l15)*32 + q*8;    // within-tile frag offset
    const int ktN = (p0 + np)*4;

    auto LOADB = [&](int ktl, short8* dst) {
        const u16* tb = g_B + (size_t)ktl*TILE_E + loff;
        dst[0] = *(const short8*)(tb);          // cols colbase..+15
        dst[1] = *(const short8*)(tb + 512);    // cols colbase+16..+31
    };

    // Two 4-kt buffer sets; phase p computes from CUR while all 8 loads for phase p+1
    // go to NXT. All indices compile-time after unroll (rule: no runtime-indexed regs).
    short8 Abuf[4][2], Bbuf[4][2];

#define DO_PHASE(CUR, NXT, PIDX, KTNXT)                                               \
    {                                                                                  \
        _Pragma("unroll")                                                              \
        for (int s = 0; s < 4; ++s) {                                                  \
            const int kl = (KTNXT) + s;                                                \
            LOADB(kl < ktN ? kl : ktN - 1, NXT[s]);                                    \
        }                                                                              \
        floatx4 aj[4][2];                                                              \
        _Pragma("unroll")                                                              \
        for (int mt = 0; mt < 4; ++mt) {  /* ks=0: C-in = 0 */                         \
            aj[mt][0] = __builtin_amdgcn_mfma_f32_16x16x32_bf16(af[0][mt], CUR[0][0], fzero, 0,0,0); \
            aj[mt][1] = __builtin_amdgcn_mfma_f32_16x16x32_bf16(af[0][mt], CUR[0][1], fzero, 0,0,0); \
        }                                                                              \
        _Pragma("unroll")                                                              \
        for (int mt = 0; mt < 4; ++mt) {                                               \
            aj[mt][0] = __builtin_amdgcn_mfma_f32_16x16x32_bf16(af[1][mt], CUR[1][0], aj[mt][0], 0,0,0); \
            aj[mt][1] = __builtin_amdgcn_mfma_f32_16x16x32_bf16(af[1][mt], CUR[1][1], aj[mt][1], 0,0,0); \
        }                                                                              \
        _Pragma("unroll")                                                              \
        for (int mt = 0; mt < 4; ++mt) {                                               \
            aj[mt][0] = __builtin_amdgcn_mfma_f32_16x16x32_bf16(af[2][mt], CUR[2][0], aj[mt][0], 0,0,0); \
            aj[mt][1] = __builtin_amdgcn_mfma_f32_16x16x32_bf16(af[2][mt], CUR[2][1], aj[mt][1], 0,0,0); \
        }                                                                              \
        _Pragma("unroll")                                                              \
        for (int mt = 0; mt < 4; ++mt) {                                               \
            aj[mt][0] = __builtin_amdgcn_mfma_f32_16x16x32_bf16(af[3][mt], CUR[3][0], aj[mt][0], 0,0,0); \
            aj[mt][1] = __builtin_amdgcn_mfma_f32_16x16x32_bf16(af[3][mt], CUR[3][1], aj[mt][1], 0,0,0); \
        }                                                                              \
        _Pragma("unroll")                                                              \
        for (int mt = 0; mt < 4; ++mt) {                                               \
            floatx4 xjv;                                                               \
            _Pragma("unroll")                                                          \
            for (int r = 0; r < 4; ++r) {                                              \
                const int rl = wm*64 + mt*16 + q*4 + r;   /* C/D: row = q*4 + reg */   \
                xjv[r] = ((PIDX) < 128)                                                \
                    ? __uint_as_float(((unsigned int)xs[rl*XS_STRIDE + (PIDX)]) << 16) \
                    : 1.0f;                                                            \
            }                                                                          \
            acc[mt][0] += xjv * aj[mt][0];                                             \
            acc[mt][1] += xjv * aj[mt][1];                                             \
        }                                                                              \
    }

    int kt = p0*4;
#pragma unroll
    for (int s = 0; s < 4; ++s) LOADB(kt + s, Abuf[s]);   // phase p0 (always valid)

    const int pairs = np >> 1;
    for (int j = 0; j < pairs; ++j) {
        const int p = p0 + 2*j;
        DO_PHASE(Abuf, Bbuf, p,     kt + 4);
        DO_PHASE(Bbuf, Abuf, p + 1, kt + 8);
        kt += 8;
    }
    if (np & 1) {                       // final odd phase (slice 0): consumes Abuf
        const int p = p0 + np - 1;
        DO_PHASE(Abuf, Bbuf, p, kt + 4);
    }
#undef DO_PHASE

    // 8 K-slices reduce via device-scope atomics directly into out (pre-filled = bb).
#pragma unroll
    for (int mt = 0; mt < 4; ++mt)
#pragma unroll
        for (int nt = 0; nt < 2; ++nt) {
            const int col = colbase + nt*16 + l15;        // C/D: col = lane&15
#pragma unroll
            for (int r = 0; r < 4; ++r) {
                const int row = row0 + wm*64 + mt*16 + q*4 + r;
                atomicAdd(&out[((size_t)row << 7) + col], acc[mt][nt][r]);
            }
        }
}

extern "C" void kernel_launch(void* const* d_in, const int* in_sizes, int n_in,
                              void* d_out, int out_size, void* d_ws, size_t ws_size,
                              hipStream_t stream) {
    (void)in_sizes; (void)n_in; (void)out_size; (void)d_ws; (void)ws_size;
    const float* x  = (const float*)d_in[0];
    const float* Wb = (const float*)d_in[1];
    const float* bb = (const float*)d_in[2];
    const float* Ww = (const float*)d_in[3];
    const float* bw = (const float*)d_in[4];
    float* out = (float*)d_out;

    prep_kernel<<<dim3(NKT),  dim3(256), 0, stream>>>(Ww, Wb, bw, bb, out);
    gemm_kernel<<<dim3(1024), dim3(256), 0, stream>>>(x, out);
}

// Round 9
// 116.116 us; speedup vs baseline: 1.0952x; 1.0952x over previous
//
#include <hip/hip_runtime.h>
#include <stdint.h>
#include <stddef.h>

// y[n,o] = sum_i x[n,i]*W[n,i,o] + b[n,o];  W = (x@Ww+bw) reshaped; b = x@Wb+bb.
// => Y = A@B (+bb): A[n, j*128+i] = x[n,i]*x[n,j]; B = Ww viewed [16384,128] row-major,
//    K-tail of 128: A[n,16384+i]=x[n,i], B[16384+i,o]=Wb[i,o]+bw[i*128+o].
// Per-j-phase factoring: aj = X_rows·B_j with raw-x fragments, acc += x[row,j]*aj.
// ROUND 16: r15 post-mortem — (a) atomics into out cost +11.6us inside gemm (51->62.6,
// FETCH/VGPR unchanged): revert to r13 plain-store epilogue + finish. (b) non-gemm
// ~60us is FIXED harness cost (deleting a kernel moved it 5us): stop chasing; target
// gemm's 51us. (c) Recount: per phase per wave ~400cy issue (155 MFMA + 93 DS + 120
// VALU + 30 VMEM) with serial deps; measured ~925cy per SIMD phase-pair = 2 waves with
// no cross-wave overlap -> issue/latency-bound at 2 waves/SIMD. Launch-attr occupancy
// raises all failed (r8/r9/r11 spilled, r13 no-op). NEW LEVER: 512-thread blocks
// (8 waves) at the proven 2-blocks/CU residency = 16 waves/CU = 4 waves/SIMD. Tile
// 128x128 (wave grid 2x4, per-wave 64x32 code byte-identical), grid 512 = slice(8) x
// rb(64) exactly 2/CU. Worst case 1 block/CU = 8 waves/CU > today's 5.5 (protected).

#define NROWS   8192
#define NKT     516            // (16384+128)/32 K-tiles
#define TILE_E  4096           // 128 cols x 32 kk per K-tile image (u16)
#define XS_STRIDE 136          // 128 + 8 pad for LDS x tile
#define LS_STRIDE 136
#define BM      128
#define NSLICE  8

typedef unsigned short u16;
typedef short short8 __attribute__((ext_vector_type(8)));
typedef unsigned short ushort8 __attribute__((ext_vector_type(8)));
typedef float floatx4 __attribute__((ext_vector_type(4)));

// Module-scope scratch (BSS; independent of d_ws — rounds 1-3 showed ws hazards).
__device__ __align__(16) u16   g_B[(size_t)NKT * TILE_E];                    // 4.2 MB bf16 B image
__device__ __align__(16) float g_P[(size_t)NSLICE * NROWS * 128];            // 33.5 MB fp32 partials

__device__ __forceinline__ u16 f2bf_rne(float f) {
    unsigned int u = __float_as_uint(f);
    u += 0x7fffu + ((u >> 16) & 1u);
    return (u16)(u >> 16);
}

// ---------------- prep: g_B[kt][o][kk] = B[kt*32+kk][o], coalesced via LDS transpose.
__global__ __launch_bounds__(256) void prep_kernel(
    const float* __restrict__ Ww, const float* __restrict__ Wb,
    const float* __restrict__ bw)
{
    __shared__ __align__(16) u16 ls[32 * LS_STRIDE];
    const int kt = blockIdx.x;
    const int t  = threadIdx.x;

    // load 16 contiguous floats -> bf16, store to ls[kk][o] (padded stride)
    float v[16];
    if (kt < 512) {
        const float* src = Ww + (size_t)(kt >> 2)*16384 + (size_t)(kt & 3)*32*128 + t*16;
#pragma unroll
        for (int c = 0; c < 4; ++c) {
            const floatx4 f4 = *(const floatx4*)(src + c*4);
#pragma unroll
            for (int e = 0; e < 4; ++e) v[c*4 + e] = f4[e];
        }
    } else {
        const size_t base = (size_t)(kt - 512)*32*128 + t*16;
        const float* s1 = Wb + base;
        const float* s2 = bw + base;
#pragma unroll
        for (int c = 0; c < 4; ++c) {
            const floatx4 a = *(const floatx4*)(s1 + c*4);
            const floatx4 b = *(const floatx4*)(s2 + c*4);
#pragma unroll
            for (int e = 0; e < 4; ++e) v[c*4 + e] = a[e] + b[e];
        }
    }
    {
        const int kk = t >> 3;            // f = t*16 -> kk = f>>7
        const int o0 = (t & 7) * 16;      // f & 127
        ushort8 w0, w1;
#pragma unroll
        for (int e = 0; e < 8; ++e) { w0[e] = f2bf_rne(v[e]); w1[e] = f2bf_rne(v[8+e]); }
        *(ushort8*)&ls[kk*LS_STRIDE + o0]     = w0;
        *(ushort8*)&ls[kk*LS_STRIDE + o0 + 8] = w1;
    }
    __syncthreads();
    // write out [o][kk]: thread t covers d = t*16..+15 -> o = t>>1, kk = (t&1)*16..+15
    {
        const int o   = t >> 1;
        const int kk0 = (t & 1) * 16;
        ushort8 w0, w1;
#pragma unroll
        for (int e = 0; e < 8; ++e) {
            w0[e] = ls[(kk0 + e)*LS_STRIDE + o];
            w1[e] = ls[(kk0 + 8 + e)*LS_STRIDE + o];
        }
        u16* outp = g_B + (size_t)kt*TILE_E + t*16;
        ((ushort8*)outp)[0] = w0; ((ushort8*)outp)[1] = w1;
    }
}

// ---------------- gemm: 8-wave block, 128x128 tile, dbuf B prefetch ----------------
// grid 512 = slice(8) x rowblock(64); block tile 128 rows x 128 cols; 2 blocks/CU
// (16 waves/CU = 4 waves/SIMD). slice = b>>6: consecutive IDs share slice (r7-proven).
// Per wave: 64x32 sub-tile, structure identical to r13's proven DO_PHASE pipeline.
__global__ __launch_bounds__(512, 2) void gemm_kernel(const float* __restrict__ x)
{
    __shared__ __align__(16) u16 xs[BM * XS_STRIDE];

    const int b     = blockIdx.x;
    const int slice = b >> 6;         // 0..7
    const int rb    = b & 63;         // 0..63
    const int row0  = rb * BM;
    const int tid   = threadIdx.x;
    const int lane  = tid & 63;
    const int wave  = tid >> 6;       // 0..7
    const int wm    = wave >> 2;      // row group: rows [wm*64, +64)
    const int wc    = wave & 3;       // col subgroup: cols [wc*32, +32)
    const int l15   = lane & 15;
    const int q     = lane >> 4;

    // stage x[row0..+128)[0..128) fp32 -> bf16 xs (512 threads: 4 iters)
#pragma unroll
    for (int it = 0; it < 4; ++it) {
        const int c  = it*512 + tid;
        const int r  = c >> 4;
        const int c8 = (c & 15) * 8;
        const float* sp = x + ((size_t)(row0 + r) << 7) + c8;
        const floatx4 f0 = *(const floatx4*)(sp);
        const floatx4 f1 = *(const floatx4*)(sp + 4);
        ushort8 w;
#pragma unroll
        for (int e = 0; e < 4; ++e) { w[e] = f2bf_rne(f0[e]); w[4+e] = f2bf_rne(f1[e]); }
        *(ushort8*)&xs[r*XS_STRIDE + c8] = w;
    }
    __syncthreads();

    // A-fragments cached (phase-invariant): af[ks][mt], A[m=l15][k=q*8+e]
    short8 af[4][4];
#pragma unroll
    for (int ks = 0; ks < 4; ++ks)
#pragma unroll
        for (int mt = 0; mt < 4; ++mt)
            af[ks][mt] = *(const short8*)&xs[(wm*64 + mt*16 + l15)*XS_STRIDE + ks*32 + q*8];

    const floatx4 fzero = {0.f, 0.f, 0.f, 0.f};
    floatx4 acc[4][2];
#pragma unroll
    for (int i = 0; i < 4; ++i) { acc[i][0] = fzero; acc[i][1] = fzero; }

    // phase partition: 129 phases over 8 slices (17,16,16,16,16,16,16,16)
    const int p0 = slice*16 + (slice ? 1 : 0);
    const int np = slice ? 16 : 17;

    const int colbase = wc*32;
    const size_t loff = (size_t)(colbase + l15)*32 + q*8;    // within-tile frag offset
    const int ktN = (p0 + np)*4;

    auto LOADB = [&](int ktl, short8* dst) {
        const u16* tb = g_B + (size_t)ktl*TILE_E + loff;
        dst[0] = *(const short8*)(tb);          // cols colbase..+15
        dst[1] = *(const short8*)(tb + 512);    // cols colbase+16..+31
    };

    // Two 4-kt buffer sets; phase p computes from CUR while all 8 loads for phase p+1
    // go to NXT. All indices compile-time after unroll (rule: no runtime-indexed regs).
    short8 Abuf[4][2], Bbuf[4][2];

#define DO_PHASE(CUR, NXT, PIDX, KTNXT)                                               \
    {                                                                                  \
        _Pragma("unroll")                                                              \
        for (int s = 0; s < 4; ++s) {                                                  \
            const int kl = (KTNXT) + s;                                                \
            LOADB(kl < ktN ? kl : ktN - 1, NXT[s]);                                    \
        }                                                                              \
        floatx4 aj[4][2];                                                              \
        _Pragma("unroll")                                                              \
        for (int mt = 0; mt < 4; ++mt) {  /* ks=0: C-in = 0 */                         \
            aj[mt][0] = __builtin_amdgcn_mfma_f32_16x16x32_bf16(af[0][mt], CUR[0][0], fzero, 0,0,0); \
            aj[mt][1] = __builtin_amdgcn_mfma_f32_16x16x32_bf16(af[0][mt], CUR[0][1], fzero, 0,0,0); \
        }                                                                              \
        _Pragma("unroll")                                                              \
        for (int mt = 0; mt < 4; ++mt) {                                               \
            aj[mt][0] = __builtin_amdgcn_mfma_f32_16x16x32_bf16(af[1][mt], CUR[1][0], aj[mt][0], 0,0,0); \
            aj[mt][1] = __builtin_amdgcn_mfma_f32_16x16x32_bf16(af[1][mt], CUR[1][1], aj[mt][1], 0,0,0); \
        }                                                                              \
        _Pragma("unroll")                                                              \
        for (int mt = 0; mt < 4; ++mt) {                                               \
            aj[mt][0] = __builtin_amdgcn_mfma_f32_16x16x32_bf16(af[2][mt], CUR[2][0], aj[mt][0], 0,0,0); \
            aj[mt][1] = __builtin_amdgcn_mfma_f32_16x16x32_bf16(af[2][mt], CUR[2][1], aj[mt][1], 0,0,0); \
        }                                                                              \
        _Pragma("unroll")                                                              \
        for (int mt = 0; mt < 4; ++mt) {                                               \
            aj[mt][0] = __builtin_amdgcn_mfma_f32_16x16x32_bf16(af[3][mt], CUR[3][0], aj[mt][0], 0,0,0); \
            aj[mt][1] = __builtin_amdgcn_mfma_f32_16x16x32_bf16(af[3][mt], CUR[3][1], aj[mt][1], 0,0,0); \
        }                                                                              \
        _Pragma("unroll")                                                              \
        for (int mt = 0; mt < 4; ++mt) {                                               \
            floatx4 xjv;                                                               \
            _Pragma("unroll")                                                          \
            for (int r = 0; r < 4; ++r) {                                              \
                const int rl = wm*64 + mt*16 + q*4 + r;   /* C/D: row = q*4 + reg */   \
                xjv[r] = ((PIDX) < 128)                                                \
                    ? __uint_as_float(((unsigned int)xs[rl*XS_STRIDE + (PIDX)]) << 16) \
                    : 1.0f;                                                            \
            }                                                                          \
            acc[mt][0] += xjv * aj[mt][0];                                             \
            acc[mt][1] += xjv * aj[mt][1];                                             \
        }                                                                              \
    }

    int kt = p0*4;
#pragma unroll
    for (int s = 0; s < 4; ++s) LOADB(kt + s, Abuf[s]);   // phase p0 (always valid)

    const int pairs = np >> 1;
    for (int j = 0; j < pairs; ++j) {
        const int p = p0 + 2*j;
        DO_PHASE(Abuf, Bbuf, p,     kt + 4);
        DO_PHASE(Bbuf, Abuf, p + 1, kt + 8);
        kt += 8;
    }
    if (np & 1) {                       // final odd phase (slice 0): consumes Abuf
        const int p = p0 + np - 1;
        DO_PHASE(Abuf, Bbuf, p, kt + 4);
    }
#undef DO_PHASE

    // slice-private plain stores (no atomics; region fully overwritten -> no zeroing)
    float* op = g_P + (size_t)slice * ((size_t)NROWS * 128);
#pragma unroll
    for (int mt = 0; mt < 4; ++mt)
#pragma unroll
        for (int nt = 0; nt < 2; ++nt) {
            const int col = colbase + nt*16 + l15;        // C/D: col = lane&15
#pragma unroll
            for (int r = 0; r < 4; ++r) {
                const int row = row0 + wm*64 + mt*16 + q*4 + r;
                op[((size_t)row << 7) + col] = acc[mt][nt][r];
            }
        }
}

// ---------------- finish: reduce 8 slice partials, + bb, write fp32 ----------------
__global__ __launch_bounds__(256) void finish_kernel(
    const float* __restrict__ bb, float* __restrict__ out)
{
    const int flat = (blockIdx.x*256 + threadIdx.x) * 8;
    floatx4 s0 = {0.f, 0.f, 0.f, 0.f};
    floatx4 s1 = {0.f, 0.f, 0.f, 0.f};
#pragma unroll
    for (int s = 0; s < NSLICE; ++s) {
        const float* p = g_P + (size_t)s * ((size_t)NROWS * 128) + flat;
        const floatx4 a = *(const floatx4*)p;
        const floatx4 c = *(const floatx4*)(p + 4);
#pragma unroll
        for (int e = 0; e < 4; ++e) { s0[e] += a[e]; s1[e] += c[e]; }
    }
    const floatx4 b0 = *(const floatx4*)(bb + (flat & 127));
    const floatx4 b1 = *(const floatx4*)(bb + (flat & 127) + 4);
    floatx4 o0, o1;
#pragma unroll
    for (int e = 0; e < 4; ++e) { o0[e] = s0[e] + b0[e]; o1[e] = s1[e] + b1[e]; }
    *(floatx4*)(out + flat)     = o0;
    *(floatx4*)(out + flat + 4) = o1;
}

extern "C" void kernel_launch(void* const* d_in, const int* in_sizes, int n_in,
                              void* d_out, int out_size, void* d_ws, size_t ws_size,
                              hipStream_t stream) {
    (void)in_sizes; (void)n_in; (void)out_size; (void)d_ws; (void)ws_size;
    const float* x  = (const float*)d_in[0];
    const float* Wb = (const float*)d_in[1];
    const float* bb = (const float*)d_in[2];
    const float* Ww = (const float*)d_in[3];
    const float* bw = (const float*)d_in[4];
    float* out = (float*)d_out;

    prep_kernel  <<<dim3(NKT),            dim3(256), 0, stream>>>(Ww, Wb, bw);
    gemm_kernel  <<<dim3(512),            dim3(512), 0, stream>>>(x);
    finish_kernel<<<dim3(NROWS*128/2048), dim3(256), 0, stream>>>(bb, out);
}